// Round 1
// baseline (1721.834 us; speedup 1.0000x reference)
//
#include <hip/hip_runtime.h>
#include <cstdint>
#include <cstddef>

// ---------------------------------------------------------------------------
// SCM_MLP: 4 layers of  out = relu(out @ (W*mask)^T + exp(mu + sigma*z))
// B = H = 4096, L = 4.  Output: concat of per-layer activations [B, L*H] fp32.
//
// Strategy: bf16 MFMA GEMM (m97 structure: 128x128 tile, BK=32,
// global_load_lds width=16, XOR-swizzled LDS to kill bank conflicts),
// fused noise+relu epilogue writing fp32 out + bf16 next-layer input.
// ---------------------------------------------------------------------------

typedef __bf16 bf16x8 __attribute__((ext_vector_type(8)));
typedef float  f32x4  __attribute__((ext_vector_type(4)));

constexpr int HDIM = 4096;           // feature dim (= K = N)
constexpr int BDIM = 4096;           // batch (= M)
constexpr int LDIM = 4;              // layers
constexpr int OUTSTRIDE = LDIM * HDIM;  // 16384 floats per output row

__device__ __forceinline__ unsigned short f2bf(float f) {
    union { float f; unsigned int u; } v; v.f = f;
    unsigned int u = v.u;
    return (unsigned short)((u + 0x7FFFu + ((u >> 16) & 1u)) >> 16);  // RNE
}

// global -> LDS direct copy, 16B per lane.  LDS dest = base + lane*16.
#define GLD16(gp, lp)                                                        \
    __builtin_amdgcn_global_load_lds(                                        \
        (__attribute__((address_space(1))) void*)(uintptr_t)(const void*)(gp), \
        (__attribute__((address_space(3))) void*)(unsigned int)(uintptr_t)(void*)(lp), \
        16, 0, 0)

// ---------------------------------------------------------------------------
// elementwise converters
// ---------------------------------------------------------------------------
__global__ void cvt_act_kernel(const float* __restrict__ x,
                               unsigned short* __restrict__ o) {
    size_t i = ((size_t)blockIdx.x * blockDim.x + threadIdx.x) * 4;
    const float4 v = *reinterpret_cast<const float4*>(x + i);
    ushort4 r;
    r.x = f2bf(v.x); r.y = f2bf(v.y); r.z = f2bf(v.z); r.w = f2bf(v.w);
    *reinterpret_cast<ushort4*>(o + i) = r;
}

__global__ void cvt_w_kernel(const float* __restrict__ w,
                             const float* __restrict__ m,
                             unsigned short* __restrict__ o) {
    size_t i = ((size_t)blockIdx.x * blockDim.x + threadIdx.x) * 4;
    const float4 wv = *reinterpret_cast<const float4*>(w + i);
    const float4 mv = *reinterpret_cast<const float4*>(m + i);
    ushort4 r;
    r.x = f2bf(wv.x * mv.x); r.y = f2bf(wv.y * mv.y);
    r.z = f2bf(wv.z * mv.z); r.w = f2bf(wv.w * mv.w);
    *reinterpret_cast<ushort4*>(o + i) = r;
}

// ---------------------------------------------------------------------------
// GEMM + noise + relu.  C[m,n] = sum_k A[m,k]*W[n,k]; A,W bf16 K-contiguous.
// Block: 256 threads = 4 waves, 128x128 tile, BK=32.
// Wave (2x2 grid) owns 64x64 = 4x4 tiles of 16x16 via mfma_f32_16x16x32_bf16.
// LDS tiles are [128][32] bf16, with the 4 16B k-chunks of each row stored
// XOR-swizzled: slot (r, c) holds global chunk c ^ (r&3) ^ ((r>>2)&3).
// -> ds_read_b128 lands 2 lanes/bank (free); global_load_lds stays contiguous.
// ---------------------------------------------------------------------------
__global__ __launch_bounds__(256) void gemm_layer(
    const unsigned short* __restrict__ A,    // [BDIM, HDIM] bf16 activations
    const unsigned short* __restrict__ W,    // [HDIM, HDIM] bf16 masked weights
    const float* __restrict__ mu,            // [HDIM]
    const float* __restrict__ sg,            // [HDIM]
    const float* __restrict__ z,             // [BDIM, HDIM] fp32
    float* __restrict__ out,                 // [BDIM, OUTSTRIDE] fp32
    int outCol0,                             // layer*HDIM
    unsigned short* __restrict__ actOut)     // [BDIM, HDIM] bf16 or nullptr
{
    __shared__ unsigned short sA[128 * 32];
    __shared__ unsigned short sW[128 * 32];

    const int tid  = threadIdx.x;
    const int wave = tid >> 6;
    const int lane = tid & 63;
    const int quad = lane >> 4;
    const int l16  = lane & 15;

    const int bm0 = blockIdx.y << 7;
    const int bn0 = blockIdx.x << 7;

    // ---- staging addressing (constant over K except the k0 advance) ----
    const int rsub = lane >> 2;                                   // 0..15
    const int kch  = (lane & 3) ^ (rsub & 3) ^ ((rsub >> 2) & 3); // swizzled src chunk
    const int c0   = wave << 1;                                   // this wave's chunks

    const unsigned short* gA0 = A + (size_t)(bm0 + (c0 << 4)        + rsub) * HDIM + (kch << 3);
    const unsigned short* gA1 = A + (size_t)(bm0 + ((c0 + 1) << 4)  + rsub) * HDIM + (kch << 3);
    const unsigned short* gW0 = W + (size_t)(bn0 + (c0 << 4)        + rsub) * HDIM + (kch << 3);
    const unsigned short* gW1 = W + (size_t)(bn0 + ((c0 + 1) << 4)  + rsub) * HDIM + (kch << 3);

    unsigned short* sA0 = &sA[c0 << 9];
    unsigned short* sA1 = &sA[(c0 + 1) << 9];
    unsigned short* sW0 = &sW[c0 << 9];
    unsigned short* sW1 = &sW[(c0 + 1) << 9];

    // ---- fragment read addressing ----
    const int wm = (wave >> 1) << 6;    // wave row offset in tile
    const int wn = (wave & 1) << 6;     // wave col offset in tile
    const int chunkR = quad ^ (l16 & 3) ^ (l16 >> 2);   // un-swizzle on read
    const int aOff = ((wm + l16) << 5) + (chunkR << 3); // elems
    const int wOff = ((wn + l16) << 5) + (chunkR << 3);

    f32x4 acc[4][4] = {};

    for (int k0 = 0; k0 < HDIM; k0 += 32) {
        __syncthreads();                      // prev iter's reads done
        GLD16(gA0 + k0, sA0);
        GLD16(gA1 + k0, sA1);
        GLD16(gW0 + k0, sW0);
        GLD16(gW1 + k0, sW1);
        __syncthreads();                      // drains vmcnt -> tiles visible

        bf16x8 af[4], wf[4];
#pragma unroll
        for (int t = 0; t < 4; ++t)
            af[t] = *reinterpret_cast<const bf16x8*>(&sA[aOff + (t << 9)]);
#pragma unroll
        for (int u = 0; u < 4; ++u)
            wf[u] = *reinterpret_cast<const bf16x8*>(&sW[wOff + (u << 9)]);
#pragma unroll
        for (int t = 0; t < 4; ++t)
#pragma unroll
            for (int u = 0; u < 4; ++u)
                acc[t][u] = __builtin_amdgcn_mfma_f32_16x16x32_bf16(
                    af[t], wf[u], acc[t][u], 0, 0, 0);
    }

    // ---- epilogue: + exp(mu + sigma*z), relu, store fp32 + bf16 ----
    float munv[4], sgnv[4];
    int   ncol[4];
#pragma unroll
    for (int u = 0; u < 4; ++u) {
        ncol[u] = bn0 + wn + (u << 4) + l16;
        munv[u] = mu[ncol[u]];
        sgnv[u] = sg[ncol[u]];
    }

#pragma unroll
    for (int t = 0; t < 4; ++t) {
#pragma unroll
        for (int r = 0; r < 4; ++r) {
            const int mrow = bm0 + wm + (t << 4) + (quad << 2) + r;
            const float* zr = z + (size_t)mrow * HDIM;
            float* orow = out + (size_t)mrow * OUTSTRIDE + outCol0;
#pragma unroll
            for (int u = 0; u < 4; ++u) {
                float v = acc[t][u][r] + __expf(fmaf(sgnv[u], zr[ncol[u]], munv[u]));
                v = fmaxf(v, 0.0f);
                orow[ncol[u]] = v;
                if (actOut)
                    actOut[(size_t)mrow * HDIM + ncol[u]] = f2bf(v);
            }
        }
    }
}

// ---------------------------------------------------------------------------
extern "C" void kernel_launch(void* const* d_in, const int* in_sizes, int n_in,
                              void* d_out, int out_size, void* d_ws, size_t ws_size,
                              hipStream_t stream) {
    const float* x       = (const float*)d_in[0];
    const float* weights = (const float*)d_in[1];
    const float* masks   = (const float*)d_in[2];
    const float* mu      = (const float*)d_in[3];
    const float* sigma   = (const float*)d_in[4];
    const float* z       = (const float*)d_in[5];
    float* out = (float*)d_out;

    // workspace layout (bf16): actA | actB | wbf   = 3 * 32 MB = 96 MB
    unsigned short* actA = (unsigned short*)d_ws;
    unsigned short* actB = actA + (size_t)BDIM * HDIM;
    unsigned short* wbf  = actB + (size_t)BDIM * HDIM;

    const int CVT_BLOCKS = (BDIM * HDIM / 4) / 256;   // 16384

    cvt_act_kernel<<<CVT_BLOCKS, 256, 0, stream>>>(x, actA);

    unsigned short* cur = actA;
    unsigned short* nxt = actB;
    for (int l = 0; l < LDIM; ++l) {
        cvt_w_kernel<<<CVT_BLOCKS, 256, 0, stream>>>(
            weights + (size_t)l * HDIM * HDIM,
            masks   + (size_t)l * HDIM * HDIM, wbf);

        dim3 grid(HDIM / 128, BDIM / 128);   // (32, 32)
        gemm_layer<<<grid, 256, 0, stream>>>(
            cur, wbf,
            mu + (size_t)l * HDIM, sigma + (size_t)l * HDIM,
            z + (size_t)l * BDIM * HDIM,
            out, l * HDIM,
            (l == LDIM - 1) ? nullptr : nxt);

        unsigned short* tmp = cur; cur = nxt; nxt = tmp;
    }
}

// Round 2
// 1696.155 us; speedup vs baseline: 1.0151x; 1.0151x over previous
//
#include <hip/hip_runtime.h>
#include <cstdint>
#include <cstddef>

// ---------------------------------------------------------------------------
// SCM_MLP: 4 layers of  out = relu(out @ (W*mask)^T + exp(mu + sigma*z))
// B = H = 4096, L = 4.  Output: concat of per-layer activations [B, L*H] fp32.
//
// R2: LDS double-buffered K-loop (one barrier/iter, prefetch overlaps compute)
// on top of the R1 structure (128x128 tile, BK=32, global_load_lds width=16,
// XOR-swizzled LDS, fused noise+relu epilogue).
// ---------------------------------------------------------------------------

typedef __bf16 bf16x8 __attribute__((ext_vector_type(8)));
typedef float  f32x4  __attribute__((ext_vector_type(4)));

constexpr int HDIM = 4096;           // feature dim (= K = N)
constexpr int BDIM = 4096;           // batch (= M)
constexpr int LDIM = 4;              // layers
constexpr int OUTSTRIDE = LDIM * HDIM;  // 16384 floats per output row

__device__ __forceinline__ unsigned short f2bf(float f) {
    union { float f; unsigned int u; } v; v.f = f;
    unsigned int u = v.u;
    return (unsigned short)((u + 0x7FFFu + ((u >> 16) & 1u)) >> 16);  // RNE
}

// global -> LDS direct copy, 16B per lane.  LDS dest = base + lane*16.
#define GLD16(gp, lp)                                                        \
    __builtin_amdgcn_global_load_lds(                                        \
        (__attribute__((address_space(1))) void*)(uintptr_t)(const void*)(gp), \
        (__attribute__((address_space(3))) void*)(unsigned int)(uintptr_t)(void*)(lp), \
        16, 0, 0)

// ---------------------------------------------------------------------------
// elementwise converters
// ---------------------------------------------------------------------------
__global__ void cvt_act_kernel(const float* __restrict__ x,
                               unsigned short* __restrict__ o) {
    size_t i = ((size_t)blockIdx.x * blockDim.x + threadIdx.x) * 4;
    const float4 v = *reinterpret_cast<const float4*>(x + i);
    ushort4 r;
    r.x = f2bf(v.x); r.y = f2bf(v.y); r.z = f2bf(v.z); r.w = f2bf(v.w);
    *reinterpret_cast<ushort4*>(o + i) = r;
}

__global__ void cvt_w_kernel(const float* __restrict__ w,
                             const float* __restrict__ m,
                             unsigned short* __restrict__ o) {
    size_t i = ((size_t)blockIdx.x * blockDim.x + threadIdx.x) * 4;
    const float4 wv = *reinterpret_cast<const float4*>(w + i);
    const float4 mv = *reinterpret_cast<const float4*>(m + i);
    ushort4 r;
    r.x = f2bf(wv.x * mv.x); r.y = f2bf(wv.y * mv.y);
    r.z = f2bf(wv.z * mv.z); r.w = f2bf(wv.w * mv.w);
    *reinterpret_cast<ushort4*>(o + i) = r;
}

// ---------------------------------------------------------------------------
// GEMM + noise + relu.  C[m,n] = sum_k A[m,k]*W[n,k]; A,W bf16 K-contiguous.
// Block: 256 threads = 4 waves, 128x128 tile, BK=32, double-buffered LDS.
// Per iter: prefetch(next tile -> other buf), compute(cur buf), ONE barrier.
// The barrier's vmcnt(0) drain now lands after ~400 cyc of compute overlap.
// ---------------------------------------------------------------------------
__global__ __launch_bounds__(256) void gemm_layer(
    const unsigned short* __restrict__ A,    // [BDIM, HDIM] bf16 activations
    const unsigned short* __restrict__ W,    // [HDIM, HDIM] bf16 masked weights
    const float* __restrict__ mu,            // [HDIM]
    const float* __restrict__ sg,            // [HDIM]
    const float* __restrict__ z,             // [BDIM, HDIM] fp32
    float* __restrict__ out,                 // [BDIM, OUTSTRIDE] fp32
    int outCol0,                             // layer*HDIM
    unsigned short* __restrict__ actOut)     // [BDIM, HDIM] bf16 or nullptr
{
    __shared__ unsigned short sA[2][128 * 32];
    __shared__ unsigned short sW[2][128 * 32];

    const int tid  = threadIdx.x;
    const int wave = tid >> 6;
    const int lane = tid & 63;
    const int quad = lane >> 4;
    const int l16  = lane & 15;

    const int bm0 = blockIdx.y << 7;
    const int bn0 = blockIdx.x << 7;

    // ---- staging addressing ----
    const int rsub = lane >> 2;                                   // 0..15
    const int kch  = (lane & 3) ^ (rsub & 3) ^ ((rsub >> 2) & 3); // swizzled src chunk
    const int c0   = wave << 1;                                   // this wave's chunks

    const unsigned short* gA0 = A + (size_t)(bm0 + (c0 << 4)        + rsub) * HDIM + (kch << 3);
    const unsigned short* gA1 = A + (size_t)(bm0 + ((c0 + 1) << 4)  + rsub) * HDIM + (kch << 3);
    const unsigned short* gW0 = W + (size_t)(bn0 + (c0 << 4)        + rsub) * HDIM + (kch << 3);
    const unsigned short* gW1 = W + (size_t)(bn0 + ((c0 + 1) << 4)  + rsub) * HDIM + (kch << 3);

    // ---- fragment read addressing ----
    const int wm = (wave >> 1) << 6;    // wave row offset in tile
    const int wn = (wave & 1) << 6;     // wave col offset in tile
    const int chunkR = quad ^ (l16 & 3) ^ (l16 >> 2);   // un-swizzle on read
    const int aOff = ((wm + l16) << 5) + (chunkR << 3); // elems
    const int wOff = ((wn + l16) << 5) + (chunkR << 3);

    f32x4 acc[4][4] = {};

#define STAGE(buf, k)                                   \
    do {                                                \
        GLD16(gA0 + (k), &sA[buf][c0 << 9]);            \
        GLD16(gA1 + (k), &sA[buf][(c0 + 1) << 9]);      \
        GLD16(gW0 + (k), &sW[buf][c0 << 9]);            \
        GLD16(gW1 + (k), &sW[buf][(c0 + 1) << 9]);      \
    } while (0)

#define COMP(buf)                                                              \
    do {                                                                       \
        bf16x8 af[4], wf[4];                                                   \
        _Pragma("unroll")                                                      \
        for (int t = 0; t < 4; ++t)                                            \
            af[t] = *reinterpret_cast<const bf16x8*>(&sA[buf][aOff + (t << 9)]); \
        _Pragma("unroll")                                                      \
        for (int u = 0; u < 4; ++u)                                            \
            wf[u] = *reinterpret_cast<const bf16x8*>(&sW[buf][wOff + (u << 9)]); \
        _Pragma("unroll")                                                      \
        for (int t = 0; t < 4; ++t)                                            \
            _Pragma("unroll")                                                  \
            for (int u = 0; u < 4; ++u)                                        \
                acc[t][u] = __builtin_amdgcn_mfma_f32_16x16x32_bf16(           \
                    af[t], wf[u], acc[t][u], 0, 0, 0);                         \
    } while (0)

    // prologue: stage first tile into buf0
    STAGE(0, 0);
    __syncthreads();   // buf0 visible

    for (int k0 = 0; k0 < HDIM; k0 += 64) {
        // prefetch k0+32 into buf1 while computing buf0
        STAGE(1, k0 + 32);
        COMP(0);
        __syncthreads();   // drains prefetch -> buf1 ready; all done reading buf0

        if (k0 + 64 < HDIM)
            STAGE(0, k0 + 64);
        COMP(1);
        __syncthreads();   // buf0 ready; all done reading buf1
    }

#undef STAGE
#undef COMP

    // ---- epilogue: + exp(mu + sigma*z), relu, store fp32 + bf16 ----
    float munv[4], sgnv[4];
    int   ncol[4];
#pragma unroll
    for (int u = 0; u < 4; ++u) {
        ncol[u] = bn0 + wn + (u << 4) + l16;
        munv[u] = mu[ncol[u]];
        sgnv[u] = sg[ncol[u]];
    }

#pragma unroll
    for (int t = 0; t < 4; ++t) {
#pragma unroll
        for (int r = 0; r < 4; ++r) {
            const int mrow = bm0 + wm + (t << 4) + (quad << 2) + r;
            const float* zr = z + (size_t)mrow * HDIM;
            float* orow = out + (size_t)mrow * OUTSTRIDE + outCol0;
#pragma unroll
            for (int u = 0; u < 4; ++u) {
                float v = acc[t][u][r] + __expf(fmaf(sgnv[u], zr[ncol[u]], munv[u]));
                v = fmaxf(v, 0.0f);
                orow[ncol[u]] = v;
                if (actOut)
                    actOut[(size_t)mrow * HDIM + ncol[u]] = f2bf(v);
            }
        }
    }
}

// ---------------------------------------------------------------------------
extern "C" void kernel_launch(void* const* d_in, const int* in_sizes, int n_in,
                              void* d_out, int out_size, void* d_ws, size_t ws_size,
                              hipStream_t stream) {
    const float* x       = (const float*)d_in[0];
    const float* weights = (const float*)d_in[1];
    const float* masks   = (const float*)d_in[2];
    const float* mu      = (const float*)d_in[3];
    const float* sigma   = (const float*)d_in[4];
    const float* z       = (const float*)d_in[5];
    float* out = (float*)d_out;

    // workspace layout (bf16): actA | actB | wbf   = 3 * 32 MB = 96 MB
    unsigned short* actA = (unsigned short*)d_ws;
    unsigned short* actB = actA + (size_t)BDIM * HDIM;
    unsigned short* wbf  = actB + (size_t)BDIM * HDIM;

    const int CVT_BLOCKS = (BDIM * HDIM / 4) / 256;   // 16384

    cvt_act_kernel<<<CVT_BLOCKS, 256, 0, stream>>>(x, actA);

    unsigned short* cur = actA;
    unsigned short* nxt = actB;
    for (int l = 0; l < LDIM; ++l) {
        cvt_w_kernel<<<CVT_BLOCKS, 256, 0, stream>>>(
            weights + (size_t)l * HDIM * HDIM,
            masks   + (size_t)l * HDIM * HDIM, wbf);

        dim3 grid(HDIM / 128, BDIM / 128);   // (32, 32)
        gemm_layer<<<grid, 256, 0, stream>>>(
            cur, wbf,
            mu + (size_t)l * HDIM, sigma + (size_t)l * HDIM,
            z + (size_t)l * BDIM * HDIM,
            out, l * HDIM,
            (l == LDIM - 1) ? nullptr : nxt);

        unsigned short* tmp = cur; cur = nxt; nxt = tmp;
    }
}

// Round 3
// 1531.133 us; speedup vs baseline: 1.1245x; 1.1078x over previous
//
#include <hip/hip_runtime.h>
#include <cstdint>
#include <cstddef>

// ---------------------------------------------------------------------------
// SCM_MLP: 4 layers of  out = relu(out @ (W*mask)^T + exp(mu + sigma*z))
// B = H = 4096, L = 4.  Output: concat of per-layer activations [B, L*H] fp32.
//
// R3: attack latency/concurrency starvation (R1/R2: all pipes <25% busy,
// occupancy 22.6%).  (a) 512-thread / 8-wave blocks, wave-tile 64x32 ->
// 2 waves/SIMD per block, up to 8 waves/SIMD resident.  (b) fuse next layer's
// weight conversion (W*mask -> bf16) into the gemm epilogue, killing 3
// serialized cvt_w dispatches.  Keeps: 128x128 tile, BK=32, dbuf LDS,
// global_load_lds width=16, XOR swizzle, fused noise+relu epilogue.
// ---------------------------------------------------------------------------

typedef __bf16 bf16x8 __attribute__((ext_vector_type(8)));
typedef float  f32x4  __attribute__((ext_vector_type(4)));

constexpr int HDIM = 4096;
constexpr int BDIM = 4096;
constexpr int LDIM = 4;
constexpr int OUTSTRIDE = LDIM * HDIM;

__device__ __forceinline__ unsigned short f2bf(float f) {
    union { float f; unsigned int u; } v; v.f = f;
    unsigned int u = v.u;
    return (unsigned short)((u + 0x7FFFu + ((u >> 16) & 1u)) >> 16);  // RNE
}

#define GLD16(gp, lp)                                                        \
    __builtin_amdgcn_global_load_lds(                                        \
        (__attribute__((address_space(1))) void*)(uintptr_t)(const void*)(gp), \
        (__attribute__((address_space(3))) void*)(unsigned int)(uintptr_t)(void*)(lp), \
        16, 0, 0)

// ---------------------------------------------------------------------------
// elementwise converters (used once at the head of the pipeline)
// ---------------------------------------------------------------------------
__global__ void cvt_act_kernel(const float* __restrict__ x,
                               unsigned short* __restrict__ o) {
    size_t i = ((size_t)blockIdx.x * blockDim.x + threadIdx.x) * 4;
    const float4 v = *reinterpret_cast<const float4*>(x + i);
    ushort4 r;
    r.x = f2bf(v.x); r.y = f2bf(v.y); r.z = f2bf(v.z); r.w = f2bf(v.w);
    *reinterpret_cast<ushort4*>(o + i) = r;
}

__global__ void cvt_w_kernel(const float* __restrict__ w,
                             const float* __restrict__ m,
                             unsigned short* __restrict__ o) {
    size_t i = ((size_t)blockIdx.x * blockDim.x + threadIdx.x) * 4;
    const float4 wv = *reinterpret_cast<const float4*>(w + i);
    const float4 mv = *reinterpret_cast<const float4*>(m + i);
    ushort4 r;
    r.x = f2bf(wv.x * mv.x); r.y = f2bf(wv.y * mv.y);
    r.z = f2bf(wv.z * mv.z); r.w = f2bf(wv.w * mv.w);
    *reinterpret_cast<ushort4*>(o + i) = r;
}

// ---------------------------------------------------------------------------
// GEMM + noise + relu (+ optional fused conversion of NEXT layer's weights).
// Block: 512 threads = 8 waves (2x4 over M x N), 128x128 tile, BK=32, dbuf.
// Wave-tile 64x32 = 4x2 of 16x16x32 MFMAs, acc = 32 VGPRs.
// Staging: wave w loads A rows [16w,16w+16) and W rows likewise, 1 GLD16 each.
// ---------------------------------------------------------------------------
__global__ __launch_bounds__(512) void gemm_layer(
    const unsigned short* __restrict__ A,    // [BDIM, HDIM] bf16
    const unsigned short* __restrict__ W,    // [HDIM, HDIM] bf16 (masked)
    const float* __restrict__ mu,            // [HDIM]
    const float* __restrict__ sg,            // [HDIM]
    const float* __restrict__ z,             // [BDIM, HDIM] fp32
    float* __restrict__ out,                 // [BDIM, OUTSTRIDE] fp32
    int outCol0,
    unsigned short* __restrict__ actOut,     // bf16 next-layer input or null
    const float* __restrict__ wNextF,        // next layer W fp32 or null
    const float* __restrict__ mNextF,        // next layer mask fp32 or null
    unsigned short* __restrict__ wNextOut)   // next layer bf16 out or null
{
    __shared__ unsigned short sA[2][128 * 32];
    __shared__ unsigned short sW[2][128 * 32];

    const int tid  = threadIdx.x;
    const int wave = tid >> 6;       // 0..7
    const int lane = tid & 63;
    const int quad = lane >> 4;
    const int l16  = lane & 15;

    const int bm0 = blockIdx.y << 7;
    const int bn0 = blockIdx.x << 7;

    // ---- staging addressing: wave w stages 16-row group w of each tile ----
    const int rsub = lane >> 2;                                   // 0..15
    const int kch  = (lane & 3) ^ (rsub & 3) ^ ((rsub >> 2) & 3); // swizzled src chunk

    const unsigned short* gA = A + (size_t)(bm0 + (wave << 4) + rsub) * HDIM + (kch << 3);
    const unsigned short* gW = W + (size_t)(bn0 + (wave << 4) + rsub) * HDIM + (kch << 3);

    // ---- fragment read addressing ----
    const int wm = (wave >> 2) << 6;    // 0 or 64
    const int wn = (wave & 3) << 5;     // 0,32,64,96
    const int chunkR = quad ^ (l16 & 3) ^ (l16 >> 2);   // un-swizzle on read
    const int aOff = ((wm + l16) << 5) + (chunkR << 3);
    const int wOff = ((wn + l16) << 5) + (chunkR << 3);

    f32x4 acc[4][2] = {};

#define STAGE(buf, k)                                   \
    do {                                                \
        GLD16(gA + (k), &sA[buf][wave << 9]);           \
        GLD16(gW + (k), &sW[buf][wave << 9]);           \
    } while (0)

#define COMP(buf)                                                              \
    do {                                                                       \
        bf16x8 af[4], wf[2];                                                   \
        _Pragma("unroll")                                                      \
        for (int t = 0; t < 4; ++t)                                            \
            af[t] = *reinterpret_cast<const bf16x8*>(&sA[buf][aOff + (t << 9)]); \
        _Pragma("unroll")                                                      \
        for (int u = 0; u < 2; ++u)                                            \
            wf[u] = *reinterpret_cast<const bf16x8*>(&sW[buf][wOff + (u << 9)]); \
        _Pragma("unroll")                                                      \
        for (int t = 0; t < 4; ++t)                                            \
            _Pragma("unroll")                                                  \
            for (int u = 0; u < 2; ++u)                                        \
                acc[t][u] = __builtin_amdgcn_mfma_f32_16x16x32_bf16(           \
                    af[t], wf[u], acc[t][u], 0, 0, 0);                         \
    } while (0)

    STAGE(0, 0);
    __syncthreads();

    for (int k0 = 0; k0 < HDIM; k0 += 64) {
        STAGE(1, k0 + 32);
        COMP(0);
        __syncthreads();

        if (k0 + 64 < HDIM)
            STAGE(0, k0 + 64);
        COMP(1);
        __syncthreads();
    }

#undef STAGE
#undef COMP

    // ---- epilogue: + exp(mu + sigma*z), relu, store fp32 + bf16 ----
    float munv[2], sgnv[2];
    int   ncol[2];
#pragma unroll
    for (int u = 0; u < 2; ++u) {
        ncol[u] = bn0 + wn + (u << 4) + l16;
        munv[u] = mu[ncol[u]];
        sgnv[u] = sg[ncol[u]];
    }

#pragma unroll
    for (int t = 0; t < 4; ++t) {
#pragma unroll
        for (int r = 0; r < 4; ++r) {
            const int mrow = bm0 + wm + (t << 4) + (quad << 2) + r;
            const float* zr = z + (size_t)mrow * HDIM;
            float* orow = out + (size_t)mrow * OUTSTRIDE + outCol0;
#pragma unroll
            for (int u = 0; u < 2; ++u) {
                float v = acc[t][u][r] + __expf(fmaf(sgnv[u], zr[ncol[u]], munv[u]));
                v = fmaxf(v, 0.0f);
                orow[ncol[u]] = v;
                if (actOut)
                    actOut[(size_t)mrow * HDIM + ncol[u]] = f2bf(v);
            }
        }
    }

    // ---- fused conversion of next layer's weights (W*mask -> bf16) ----
    // 1024 blocks cover 4096x4096 = 16.78M elems -> 16384/block, 32/thread.
    if (wNextF) {
        const size_t base = ((size_t)(blockIdx.y * gridDim.x + blockIdx.x) * 16384)
                          + (size_t)tid * 4;
#pragma unroll
        for (int j = 0; j < 8; ++j) {
            const size_t i = base + (size_t)j * 2048;   // 512 thr * 4 elems
            const float4 wv = *reinterpret_cast<const float4*>(wNextF + i);
            const float4 mv = *reinterpret_cast<const float4*>(mNextF + i);
            ushort4 rr;
            rr.x = f2bf(wv.x * mv.x); rr.y = f2bf(wv.y * mv.y);
            rr.z = f2bf(wv.z * mv.z); rr.w = f2bf(wv.w * mv.w);
            *reinterpret_cast<ushort4*>(wNextOut + i) = rr;
        }
    }
}

// ---------------------------------------------------------------------------
extern "C" void kernel_launch(void* const* d_in, const int* in_sizes, int n_in,
                              void* d_out, int out_size, void* d_ws, size_t ws_size,
                              hipStream_t stream) {
    const float* x       = (const float*)d_in[0];
    const float* weights = (const float*)d_in[1];
    const float* masks   = (const float*)d_in[2];
    const float* mu      = (const float*)d_in[3];
    const float* sigma   = (const float*)d_in[4];
    const float* z       = (const float*)d_in[5];
    float* out = (float*)d_out;

    const size_t NELEM = (size_t)BDIM * HDIM;           // 16.78M
    unsigned short* actA = (unsigned short*)d_ws;
    unsigned short* actB = actA + NELEM;
    unsigned short* wbA  = actB + NELEM;
    unsigned short* wbB  = wbA + NELEM;                 // needs 128 MB total

    const bool fuse = ws_size >= 4 * NELEM * sizeof(unsigned short);
    const int CVT_BLOCKS = (int)(NELEM / 4) / 256;      // 16384

    cvt_act_kernel<<<CVT_BLOCKS, 256, 0, stream>>>(x, actA);
    cvt_w_kernel<<<CVT_BLOCKS, 256, 0, stream>>>(weights, masks, wbA);

    unsigned short* cur = actA;
    unsigned short* nxt = actB;
    unsigned short* wCur = wbA;
    unsigned short* wNxt = fuse ? wbB : wbA;

    dim3 grid(HDIM / 128, BDIM / 128);   // (32, 32) = 1024 blocks

    for (int l = 0; l < LDIM; ++l) {
        if (!fuse && l > 0) {
            cvt_w_kernel<<<CVT_BLOCKS, 256, 0, stream>>>(
                weights + (size_t)l * NELEM, masks + (size_t)l * NELEM, wCur);
        }
        const bool doNext = fuse && (l + 1 < LDIM);
        gemm_layer<<<grid, 512, 0, stream>>>(
            cur, wCur,
            mu + (size_t)l * HDIM, sigma + (size_t)l * HDIM,
            z + (size_t)l * NELEM,
            out, l * HDIM,
            (l == LDIM - 1) ? nullptr : nxt,
            doNext ? weights + (size_t)(l + 1) * NELEM : nullptr,
            doNext ? masks + (size_t)(l + 1) * NELEM : nullptr,
            doNext ? wNxt : nullptr);

        unsigned short* tmp = cur; cur = nxt; nxt = tmp;
        if (fuse) { unsigned short* tw = wCur; wCur = wNxt; wNxt = tw; }
    }
}